// Round 1
// 224.621 us; speedup vs baseline: 1.0429x; 1.0429x over previous
//
#include <hip/hip_runtime.h>
#include <math.h>

// Problem constants: im [16,3,512,960] f32, disp [16,1,512,960] f32, disp in [0,40).
#define B_ 16
#define C_ 3
#define H_ 512
#define W_ 960
constexpr int HW = H_ * W_;
constexpr float EPS_ = 1e-6f;
constexpr float LOG2_BASE = 0.49978213f;  // log2(1.414)

typedef __attribute__((ext_vector_type(2))) float f2;
typedef __attribute__((ext_vector_type(4))) float f4v;

// ---------------------------------------------------------------------------
// GATHER formulation (see r2/r3 history in comments of prior version): target t
// receives from sources x in [t, t+43] with tent weight
// bw = max(0, 1 - |(x - d(x)) - t|) — identical to the reference's bilinear
// scatter incl. boundary validity. disp.min() subtraction is a global scale
// on wmap that cancels in res (|effect| ~2e-6) and is dropped.
//
// r4 changes (this round):
//  * VGPR_Count was 36 — too few registers to pipeline the LDS reads, so
//    every candidate stalled on lgkmcnt just-in-time loads (VALUBusy 67%).
//    Now: explicit depth-3 software pipeline + __launch_bounds__(256,7)
//    (7 waves/EU -> ~73 VGPR cap; LDS 20.5KB keeps 7 blocks/CU regardless).
//  * Candidate loop flattened to j = 0..43 (j=44 had identically-zero
//    weights: x = t0+44, d < 40 strictly => tx > t0+4).
//  * Staging vectorized: float4 loads (disp + 3 im channels), 240 threads.
__global__ __launch_bounds__(256, 7) void splat_kernel(const float* __restrict__ im,
                                                       const float* __restrict__ disp,
                                                       float* __restrict__ out) {
    __shared__ float  txS[4 * 257];   // tx = x - d, phase p = x&3, slot x>>2
    __shared__ float4 fS [4 * 257];   // {v0*w, v1*w, v2*w, w}

    const int row = blockIdx.x;       // b*H + y
    const int b   = row >> 9;         // H_ == 512
    const int y   = row & (H_ - 1);
    const int rowoff = row * W_;
    const float* imr = im + (size_t)b * C_ * HW + (size_t)y * W_;
    const int tid = threadIdx.x;

    // ---- stage: thread t < 240 owns pixels x = 4t..4t+3 (float4 loads);
    //      threads 240..255 fill sentinel slots t = 240..255 (only slots up
    //      to 249 are ever read: tid<=239, c<=10).
    if (tid < 240) {
        const int x0 = 4 * tid;
        f4v d4 = *(const f4v*)(disp + rowoff + x0);
        f4v c0 = *(const f4v*)(imr + x0);
        f4v c1 = *(const f4v*)(imr + HW + x0);
        f4v c2 = *(const f4v*)(imr + 2 * HW + x0);
        #pragma unroll
        for (int k = 0; k < 4; ++k) {
            float d = d4[k];
            float w = exp2f(d * LOG2_BASE);      // unshifted: scale cancels
            txS[k * 257 + tid] = (float)(x0 + k) - d;
            fS [k * 257 + tid] = make_float4(c0[k] * w, c1[k] * w, c2[k] * w, w);
        }
    } else {
        #pragma unroll
        for (int k = 0; k < 4; ++k) {
            txS[k * 257 + tid] = -1.0e9f;                    // tent weight -> 0
            fS [k * 257 + tid] = make_float4(0.f, 0.f, 0.f, 0.f);
        }
    }
    __syncthreads();

    // ---- gather: threads 0..239 own targets 4*tid .. 4*tid+3
    if (tid >= 240) return;

    const float t0 = (float)(4 * tid);
    f2 A0a = 0.f, A0b = 0.f, A1a = 0.f, A1b = 0.f, A2a = 0.f, A2b = 0.f;
    f2 AWa = 0.f, AWb = 0.f, ACa = 0.f, ACb = 0.f;
    const f2 OFFa = {0.0f, 1.0f};
    const f2 OFFb = {2.0f, 3.0f};

    const float*  txb = &txS[tid];
    const float4* fb  = &fS [tid];

    // candidate x = 4*tid + j, j in [0,43]; phase p = j&3 row, slot tid + (j>>2):
    // consecutive slots across lanes -> conflict-free.
    constexpr int NJ = 44;
    constexpr int D  = 3;             // software-pipeline depth
    float  txf[D];
    float4 ff [D];
    #pragma unroll
    for (int j = 0; j < D; ++j) {
        txf[j] = txb[(j & 3) * 257 + (j >> 2)];
        ff [j] = fb [(j & 3) * 257 + (j >> 2)];
    }
    #pragma unroll
    for (int j = 0; j < NJ; ++j) {
        const int slot = j % D;       // static after full unroll
        float  txv = txf[slot];
        float4 f   = ff [slot];
        const int jn = j + D;
        if (jn < NJ) {                // prefetch candidate j+D
            txf[slot] = txb[(jn & 3) * 257 + (jn >> 2)];
            ff [slot] = fb [(jn & 3) * 257 + (jn >> 2)];
        }

        float d0 = txv - t0;
        f2 ea = d0 - OFFa;                 // {d0, d0-1}
        f2 eb = d0 - OFFb;                 // {d0-2, d0-3}
        f2 wa, wb;
        wa.x = __builtin_fmaxf(1.0f - __builtin_fabsf(ea.x), 0.0f);
        wa.y = __builtin_fmaxf(1.0f - __builtin_fabsf(ea.y), 0.0f);
        wb.x = __builtin_fmaxf(1.0f - __builtin_fabsf(eb.x), 0.0f);
        wb.y = __builtin_fmaxf(1.0f - __builtin_fabsf(eb.y), 0.0f);
        A0a += f.x * wa;  A0b += f.x * wb;
        A1a += f.y * wa;  A1b += f.y * wb;
        A2a += f.z * wa;  A2b += f.z * wb;
        AWa += f.w * wa;  AWb += f.w * wb;
        ACa += wa;        ACb += wb;
    }

    // ---- epilogue: v_rcp (rel err ~1e-7, tolerance 2e-2), float4 stores
    float i0 = __builtin_amdgcn_rcpf(__builtin_fmaxf(AWa.x, EPS_));
    float i1 = __builtin_amdgcn_rcpf(__builtin_fmaxf(AWa.y, EPS_));
    float i2 = __builtin_amdgcn_rcpf(__builtin_fmaxf(AWb.x, EPS_));
    float i3 = __builtin_amdgcn_rcpf(__builtin_fmaxf(AWb.y, EPS_));
    float4 r0 = make_float4(A0a.x * i0, A0a.y * i1, A0b.x * i2, A0b.y * i3);
    float4 r1 = make_float4(A1a.x * i0, A1a.y * i1, A1b.x * i2, A1b.y * i3);
    float4 r2 = make_float4(A2a.x * i0, A2a.y * i1, A2b.x * i2, A2b.y * i3);
    float4 oc = make_float4(1.0f - __builtin_fminf(ACa.x, 1.0f),
                            1.0f - __builtin_fminf(ACa.y, 1.0f),
                            1.0f - __builtin_fminf(ACb.x, 1.0f),
                            1.0f - __builtin_fminf(ACb.y, 1.0f));

    float* o0 = out + (size_t)b * C_ * HW + (size_t)y * W_ + 4 * tid;
    *(float4*)(o0)          = r0;
    *(float4*)(o0 + HW)     = r1;
    *(float4*)(o0 + 2 * HW) = r2;
    *(float4*)(out + (size_t)B_ * C_ * HW + (size_t)rowoff + 4 * tid) = oc;
}

// ---------------------------------------------------------------------------
extern "C" void kernel_launch(void* const* d_in, const int* in_sizes, int n_in,
                              void* d_out, int out_size, void* d_ws, size_t ws_size,
                              hipStream_t stream) {
    (void)in_sizes; (void)n_in; (void)out_size; (void)d_ws; (void)ws_size;
    const float* im   = (const float*)d_in[0];
    const float* disp = (const float*)d_in[1];
    float* out        = (float*)d_out;

    splat_kernel<<<B_ * H_, 256, 0, stream>>>(im, disp, out);
}